// Round 2
// baseline (1068.291 us; speedup 1.0000x reference)
//
#include <hip/hip_runtime.h>
#include <cstdint>
#include <cmath>

// Problem constants
static constexpr int V_  = 50000;
static constexpr int E_  = 300;
static constexpr int C_  = 128;
static constexpr int B_  = 128;
static constexpr int SC_ = 512;
static constexpr int SE_ = 64;
static constexpr int NCOL = 768;   // [fw_gate 256 | fw_cand 128 | bw_gate 256 | bw_cand 128]
static constexpr int KP  = 320;    // K padded to 10 x 32 for MFMA

// ws layout (float offsets)
static constexpr size_t OFF_PROJ  = 0;
static constexpr size_t SZ_PROJ   = (size_t)V_ * NCOL;
static constexpr size_t OFF_WXP   = OFF_PROJ + SZ_PROJ;
static constexpr size_t SZ_WXP    = (size_t)304 * NCOL;
static constexpr size_t OFF_UALL  = OFF_WXP + SZ_WXP;
static constexpr size_t SZ_UALL   = (size_t)C_ * NCOL;
static constexpr size_t OFF_BIAS  = OFF_UALL + SZ_UALL;
static constexpr size_t SZ_BIAS   = NCOL;
static constexpr size_t OFF_ST    = OFF_BIAS + SZ_BIAS;
static constexpr size_t SZ_ST_CTX = (size_t)B_ * SC_ * C_;
static constexpr size_t SZ_ST_END = (size_t)B_ * SE_ * C_;
static constexpr size_t SZ_ST     = 2*SZ_ST_CTX + 2*SZ_ST_END;    // 75.5 MB
static constexpr size_t OFF_FEATS = OFF_ST + SZ_ST;
static constexpr size_t SZ_FEATS  = (size_t)B_ * 512;
static constexpr size_t OFF_BT    = OFF_FEATS + SZ_FEATS;
static constexpr size_t SZ_BT     = (size_t)NCOL * KP / 2 * 2;    // 2 short arrays
static constexpr size_t OFF_AWT   = OFF_BT + SZ_BT;               // att_w^T hi/lo shorts
// A_hi/A_lo (bf16) OVERLAP the states region (dead once gemm ends; recur
// zeroes its own tail rows so no global memset is needed).

typedef __attribute__((ext_vector_type(8))) short bf16x8;
typedef __attribute__((ext_vector_type(4))) float f32x4;

static __device__ __forceinline__ unsigned short f2bf_rne(float f) {
  unsigned u = __float_as_uint(f);
  unsigned r = u + 0x7fffu + ((u >> 16) & 1u);
  return (unsigned short)(r >> 16);
}

static __device__ __forceinline__ void gload_lds16(const short* g, short* l) {
  __builtin_amdgcn_global_load_lds(
      (const __attribute__((address_space(1))) void*)g,
      (__attribute__((address_space(3))) void*)l, 16, 0, 0);
}

// fast activations: __expf + v_rcp_f32 (~1e-6 rel err; logit threshold 7.4e-5)
static __device__ __forceinline__ float fast_sigmoid(float x) {
  return __builtin_amdgcn_rcpf(1.f + __expf(-x));
}
static __device__ __forceinline__ float fast_tanh(float x) {
  return fmaf(-2.f, __builtin_amdgcn_rcpf(__expf(2.f * x) + 1.f), 1.f);
}

// ---------------------------------------------------------------------------
// Pack: Wxp[304][768] fp32, Uall[128][768], bias[768]
// ---------------------------------------------------------------------------
__global__ void pack_kernel(const float* __restrict__ fw_gw, const float* __restrict__ fw_gb,
                            const float* __restrict__ fw_cw, const float* __restrict__ fw_cb,
                            const float* __restrict__ bw_gw, const float* __restrict__ bw_gb,
                            const float* __restrict__ bw_cw, const float* __restrict__ bw_cb,
                            float* __restrict__ ws) {
  int i = blockIdx.x * 256 + threadIdx.x;
  float* Wxp  = ws + OFF_WXP;
  float* Uall = ws + OFF_UALL;
  float* bias = ws + OFF_BIAS;
  if (i < 304 * NCOL) {
    int k = i / NCOL, c = i % NCOL;
    float v = 0.f;
    if (k < 300) {
      if (c < 256)      v = fw_gw[k*256 + c];
      else if (c < 384) v = fw_cw[k*128 + (c-256)];
      else if (c < 640) v = bw_gw[k*256 + (c-384)];
      else              v = bw_cw[k*128 + (c-640)];
    }
    Wxp[i] = v;
    return;
  }
  int j = i - 304 * NCOL;
  if (j >= 0 && j < 128 * NCOL) {
    int k = j / NCOL, c = j % NCOL;
    int kk = 300 + k;
    float v;
    if (c < 256)      v = fw_gw[kk*256 + c];
    else if (c < 384) v = fw_cw[kk*128 + (c-256)];
    else if (c < 640) v = bw_gw[kk*256 + (c-384)];
    else              v = bw_cw[kk*128 + (c-640)];
    Uall[j] = v;
    return;
  }
  int m = j - 128 * NCOL;
  if (m >= 0 && m < NCOL) {
    float v;
    if (m < 256)      v = fw_gb[m];
    else if (m < 384) v = fw_cb[m-256];
    else if (m < 640) v = bw_gb[m-384];
    else              v = bw_cb[m-640];
    bias[m] = v;
  }
}

// Bt hi/lo for the proj GEMM + att_w^T hi/lo for the MFMA attention
__global__ void pack_bt(const float* __restrict__ Wxp, short* __restrict__ Bthi,
                        short* __restrict__ Btlo, const float* __restrict__ att_w,
                        short* __restrict__ awt_hi, short* __restrict__ awt_lo) {
  int i = blockIdx.x * 256 + threadIdx.x;
  if (i < NCOL * KP) {
    int k = i % KP, n = i / KP;
    float v = (k < 304) ? Wxp[(size_t)k * NCOL + n] : 0.f;
    unsigned short h = f2bf_rne(v);
    float hf = __uint_as_float((unsigned)h << 16);
    unsigned short lo = f2bf_rne(v - hf);
    Bthi[i] = (short)h;
    Btlo[i] = (short)lo;
    return;
  }
  int j = i - NCOL * KP;
  if (j < 128 * 128) {
    int d = j >> 7, c = j & 127;
    float v = att_w[(size_t)c * 128 + d];   // transpose: awt[d][k=c]
    unsigned short h = f2bf_rne(v);
    float hf = __uint_as_float((unsigned)h << 16);
    unsigned short lo = f2bf_rne(v - hf);
    awt_hi[j] = (short)h;
    awt_lo[j] = (short)lo;
  }
}

__global__ void pack_emb(const float* __restrict__ emb, short* __restrict__ Ahi,
                         short* __restrict__ Alo) {
  size_t i = (size_t)blockIdx.x * 256 + threadIdx.x;
  if (i >= (size_t)V_ * KP) return;
  int k = (int)(i % KP);
  size_t row = i / KP;
  float v = (k < E_) ? emb[row * E_ + k] : 0.f;
  unsigned short h = f2bf_rne(v);
  float hf = __uint_as_float((unsigned)h << 16);
  unsigned short lo = f2bf_rne(v - hf);
  Ahi[i] = (short)h;
  Alo[i] = (short)lo;
}

// ---------------------------------------------------------------------------
// proj = emb @ Wxp via bf16x3 split MFMA (m97 structure)
// ---------------------------------------------------------------------------
__global__ __launch_bounds__(256) void gemm_mfma(
    const short* __restrict__ Ahi, const short* __restrict__ Alo,
    const short* __restrict__ Bthi, const short* __restrict__ Btlo,
    float* __restrict__ proj) {
  __shared__ short lds[16384];
  int tid = threadIdx.x, wid = tid >> 6, lane = tid & 63;
  int n0 = blockIdx.x * 128, m0 = blockIdx.y * 128;
  f32x4 acc[4][4] = {};

  int lr = lane >> 2, lc = lane & 3;
  int q0 = wid * 2, q1 = q0 + 1;
  int r0 = q0 * 16 + lr, r1 = q1 * 16 + lr;
  int am0 = m0 + r0; if (am0 > V_ - 1) am0 = V_ - 1;
  int am1 = m0 + r1; if (am1 > V_ - 1) am1 = V_ - 1;
  size_t gaOff0 = (size_t)am0 * KP + lc * 8;
  size_t gaOff1 = (size_t)am1 * KP + lc * 8;
  size_t gbOff0 = (size_t)(n0 + r0) * KP + lc * 8;
  size_t gbOff1 = (size_t)(n0 + r1) * KP + lc * 8;

  int quad = lane >> 4;
  int arow = (wid >> 1) * 64 + (lane & 15);
  int brow = (wid & 1) * 64 + (lane & 15);

  for (int k0 = 0; k0 < KP; k0 += 32) {
    gload_lds16(Ahi  + gaOff0 + k0, lds +         q0 * 512);
    gload_lds16(Ahi  + gaOff1 + k0, lds +         q1 * 512);
    gload_lds16(Alo  + gaOff0 + k0, lds +  4096 + q0 * 512);
    gload_lds16(Alo  + gaOff1 + k0, lds +  4096 + q1 * 512);
    gload_lds16(Bthi + gbOff0 + k0, lds +  8192 + q0 * 512);
    gload_lds16(Bthi + gbOff1 + k0, lds +  8192 + q1 * 512);
    gload_lds16(Btlo + gbOff0 + k0, lds + 12288 + q0 * 512);
    gload_lds16(Btlo + gbOff1 + k0, lds + 12288 + q1 * 512);
    __syncthreads();

    bf16x8 ah[4], al[4], bh[4], bl[4];
#pragma unroll
    for (int i = 0; i < 4; ++i) {
      ah[i] = *(bf16x8*)&lds[        (arow + i*16) * 32 + quad * 8];
      al[i] = *(bf16x8*)&lds[ 4096 + (arow + i*16) * 32 + quad * 8];
      bh[i] = *(bf16x8*)&lds[ 8192 + (brow + i*16) * 32 + quad * 8];
      bl[i] = *(bf16x8*)&lds[12288 + (brow + i*16) * 32 + quad * 8];
    }
#pragma unroll
    for (int i = 0; i < 4; ++i)
#pragma unroll
      for (int j = 0; j < 4; ++j) {
        acc[i][j] = __builtin_amdgcn_mfma_f32_16x16x32_bf16(ah[i], bh[j], acc[i][j], 0, 0, 0);
        acc[i][j] = __builtin_amdgcn_mfma_f32_16x16x32_bf16(ah[i], bl[j], acc[i][j], 0, 0, 0);
        acc[i][j] = __builtin_amdgcn_mfma_f32_16x16x32_bf16(al[i], bh[j], acc[i][j], 0, 0, 0);
      }
    __syncthreads();
  }

  int colb = n0 + (wid & 1) * 64 + (lane & 15);
  int rowb = m0 + (wid >> 1) * 64 + quad * 4;
#pragma unroll
  for (int i = 0; i < 4; ++i) {
    int rb = rowb + i * 16;
#pragma unroll
    for (int j = 0; j < 4; ++j) {
      int cc = colb + j * 16;
#pragma unroll
      for (int r = 0; r < 4; ++r) {
        int rr = rb + r;
        if (rr < V_) proj[(size_t)rr * NCOL + cc] = acc[i][j][r];
      }
    }
  }
}

// ---------------------------------------------------------------------------
// Recurrence v2 (pair-fused): TWO same-direction chains per WG, 256 WGs
// (exactly 1 WG/CU, 1 wave/SIMD via waves_per_eu(1,1) -> 512-VGPR budget so
// the 192 weight floats are genuinely register-resident, unlike the previous
// 124-VGPR allocation which forced AGPR/spill round-trips every step).
// The 4 barriers + LDS-reduce latency per step now amortize over 2 chains,
// and the two independent per-thread dependency chains provide the ILP that
// 1-wave/SIMD occupancy can't provide via TLP.
// ---------------------------------------------------------------------------
__global__ __attribute__((amdgpu_flat_work_group_size(256, 256),
                          amdgpu_waves_per_eu(1, 1)))
void recur_pair_kernel(
    const int* __restrict__ ctx, const int* __restrict__ endseq,
    const int* __restrict__ ctx_len, const int* __restrict__ end_len,
    const float* __restrict__ proj, const float* __restrict__ Uall,
    const float* __restrict__ bias, float* __restrict__ states) {
  __shared__ __align__(16) float h_sA[128],  h_sB[128];
  __shared__ __align__(16) float rh_sA[128], rh_sB[128];
  __shared__ __align__(16) float u_sA[128],  u_sB[128];
  __shared__ __align__(16) float pgA[8][260], pgB[8][260];
  __shared__ __align__(16) float pcA[8][132], pcB[8][132];

  int bid = blockIdx.x;
  int tid = threadIdx.x;
  const int *seqA, *seqB; int S, LA, LB, dir; float *stA, *stB;
  if (bid < 128) {                      // ctx: 64 pairs x 2 dirs
    dir = bid & 1; int p = bid >> 1;
    int b0 = p * 2, b1 = b0 + 1;
    seqA = ctx + b0 * SC_; seqB = ctx + b1 * SC_;
    S = SC_; LA = ctx_len[b0]; LB = ctx_len[b1];
    float* base = states + (dir ? SZ_ST_CTX : 0);
    stA = base + (size_t)b0 * SC_ * C_;
    stB = base + (size_t)b1 * SC_ * C_;
  } else {                              // end: 64 pairs x 2 dirs
    int q = bid - 128; dir = q & 1; int p = q >> 1;
    int b0 = p * 2, b1 = b0 + 1;
    seqA = endseq + b0 * SE_; seqB = endseq + b1 * SE_;
    S = SE_; LA = end_len[b0]; LB = end_len[b1];
    float* base = states + 2*SZ_ST_CTX + (dir ? SZ_ST_END : 0);
    stA = base + (size_t)b0 * SE_ * C_;
    stB = base + (size_t)b1 * SE_ * C_;
  }
  int dirOff = dir ? 384 : 0;
  int kg = tid >> 5, jg = tid & 31;

  // Shared weights for both chains (same dir): 192 fp32 regs/thread.
  float wg[16][8];
  float wc[16][4];
#pragma unroll
  for (int kk = 0; kk < 16; ++kk) {
    const float* up = Uall + (size_t)(kg*16 + kk) * NCOL + dirOff;
    float4 w0 = *(const float4*)(up + jg*8);
    float4 w1 = *(const float4*)(up + jg*8 + 4);
    wg[kk][0]=w0.x; wg[kk][1]=w0.y; wg[kk][2]=w0.z; wg[kk][3]=w0.w;
    wg[kk][4]=w1.x; wg[kk][5]=w1.y; wg[kk][6]=w1.z; wg[kk][7]=w1.w;
    float4 wv = *(const float4*)(up + 256 + jg*4);
    wc[kk][0]=wv.x; wc[kk][1]=wv.y; wc[kk][2]=wv.z; wc[kk][3]=wv.w;
  }
  float bias_g = bias[dirOff + tid];
  float bias_c = (tid < 128) ? bias[dirOff + 256 + tid] : 0.f;

  if (tid < 128) { h_sA[tid] = 0.f; h_sB[tid] = 0.f; }
  __syncthreads();

  int Lm = (LA > LB) ? LA : LB;

  // t = 0 x-rows for both chains
  int posA0 = dir ? (LA - 1) : 0;
  int tokA0 = seqA[posA0];
  const float* xrA0 = proj + (size_t)tokA0 * NCOL + dirOff;
  float xgA = xrA0[tid];
  float xcA = (tid < 128) ? xrA0[256 + tid] : 0.f;
  int posB0 = dir ? (LB - 1) : 0;
  int tokB0 = seqB[posB0];
  const float* xrB0 = proj + (size_t)tokB0 * NCOL + dirOff;
  float xgB = xrB0[tid];
  float xcB = (tid < 128) ? xrB0[256 + tid] : 0.f;

  for (int t = 0; t < Lm; ++t) {
    // prefetch next-step x rows (independent A/B chains -> overlapping loads)
    float xgA_n = 0.f, xcA_n = 0.f, xgB_n = 0.f, xcB_n = 0.f;
    if (t + 1 < LA) {
      int pos_n = dir ? (LA - 2 - t) : (t + 1);
      int tok_n = seqA[pos_n];
      const float* xr = proj + (size_t)tok_n * NCOL + dirOff;
      xgA_n = xr[tid];
      xcA_n = (tid < 128) ? xr[256 + tid] : 0.f;
    }
    if (t + 1 < LB) {
      int pos_n = dir ? (LB - 2 - t) : (t + 1);
      int tok_n = seqB[pos_n];
      const float* xr = proj + (size_t)tok_n * NCOL + dirOff;
      xgB_n = xr[tid];
      xcB_n = (tid < 128) ? xr[256 + tid] : 0.f;
    }

    // gate partials for both chains (shared weights)
    float aA[8] = {0.f,0.f,0.f,0.f,0.f,0.f,0.f,0.f};
    float aB[8] = {0.f,0.f,0.f,0.f,0.f,0.f,0.f,0.f};
    const float4* h4A = (const float4*)h_sA;
    const float4* h4B = (const float4*)h_sB;
#pragma unroll
    for (int q = 0; q < 4; ++q) {
      float4 hvA = h4A[kg*4 + q];
      float4 hvB = h4B[kg*4 + q];
      float heA[4] = {hvA.x, hvA.y, hvA.z, hvA.w};
      float heB[4] = {hvB.x, hvB.y, hvB.z, hvB.w};
#pragma unroll
      for (int e = 0; e < 4; ++e)
#pragma unroll
        for (int jj = 0; jj < 8; ++jj) {
          aA[jj] += heA[e] * wg[q*4 + e][jj];
          aB[jj] += heB[e] * wg[q*4 + e][jj];
        }
    }
    *(float4*)(&pgA[kg][jg*8])     = make_float4(aA[0], aA[1], aA[2], aA[3]);
    *(float4*)(&pgA[kg][jg*8 + 4]) = make_float4(aA[4], aA[5], aA[6], aA[7]);
    *(float4*)(&pgB[kg][jg*8])     = make_float4(aB[0], aB[1], aB[2], aB[3]);
    *(float4*)(&pgB[kg][jg*8 + 4]) = make_float4(aB[4], aB[5], aB[6], aB[7]);
    __syncthreads();   // B1

    float gA = xgA + bias_g;
    float gB = xgB + bias_g;
#pragma unroll
    for (int k2 = 0; k2 < 8; ++k2) { gA += pgA[k2][tid]; gB += pgB[k2][tid]; }
    gA = fast_sigmoid(gA);
    gB = fast_sigmoid(gB);

    float h_oldA = 0.f, h_oldB = 0.f;
    if (tid < 128) {
      h_oldA = h_sA[tid]; rh_sA[tid] = gA * h_oldA;
      h_oldB = h_sB[tid]; rh_sB[tid] = gB * h_oldB;
    } else {
      u_sA[tid - 128] = gA;
      u_sB[tid - 128] = gB;
    }
    __syncthreads();   // B2

    float acA[4] = {0.f, 0.f, 0.f, 0.f};
    float acB[4] = {0.f, 0.f, 0.f, 0.f};
    const float4* rh4A = (const float4*)rh_sA;
    const float4* rh4B = (const float4*)rh_sB;
#pragma unroll
    for (int q = 0; q < 4; ++q) {
      float4 rvA = rh4A[kg*4 + q];
      float4 rvB = rh4B[kg*4 + q];
      float reA[4] = {rvA.x, rvA.y, rvA.z, rvA.w};
      float reB[4] = {rvB.x, rvB.y, rvB.z, rvB.w};
#pragma unroll
      for (int e = 0; e < 4; ++e)
#pragma unroll
        for (int jj = 0; jj < 4; ++jj) {
          acA[jj] += reA[e] * wc[q*4 + e][jj];
          acB[jj] += reB[e] * wc[q*4 + e][jj];
        }
    }
    *(float4*)(&pcA[kg][jg*4]) = make_float4(acA[0], acA[1], acA[2], acA[3]);
    *(float4*)(&pcB[kg][jg*4]) = make_float4(acB[0], acB[1], acB[2], acB[3]);
    __syncthreads();   // B3

    if (tid < 128) {
      float csA = xcA + bias_c;
      float csB = xcB + bias_c;
#pragma unroll
      for (int k2 = 0; k2 < 8; ++k2) { csA += pcA[k2][tid]; csB += pcB[k2][tid]; }
      float cA = fast_tanh(csA);
      float cB = fast_tanh(csB);
      float uA = u_sA[tid];
      float uB = u_sB[tid];
      float hnA = uA * h_oldA + (1.f - uA) * cA;
      float hnB = uB * h_oldB + (1.f - uB) * cB;
      h_sA[tid] = hnA;
      h_sB[tid] = hnB;
      if (t < LA) {
        int pos = dir ? (LA - 1 - t) : t;
        stA[(size_t)pos * C_ + tid] = hnA;
      }
      if (t < LB) {
        int pos = dir ? (LB - 1 - t) : t;
        stB[(size_t)pos * C_ + tid] = hnB;
      }
    }
    __syncthreads();   // B4
    xgA = xgA_n; xcA = xcA_n;
    xgB = xgB_n; xcB = xcB_n;
  }

  for (int i = LA * C_ + tid; i < S * C_; i += 256) stA[i] = 0.f;
  for (int i = LB * C_ + tid; i < S * C_; i += 256) stB[i] = 0.f;
}

// ---------------------------------------------------------------------------
// Attention v2: MFMA bf16x3 score projection. Per WG (b, dir, arr):
// B-frags = att_w^T hi/lo in registers (wave w owns d-cols [32w,+32)).
// Chunks of 16 state rows: stage fp32 + bf16 hi/lo to LDS (1-chunk register
// prefetch), 24 mfma/wave, epilogue tanh*v + quad-shfl + spart reduce,
// online softmax (half = rows 0-7 / 8-15; halves merged at end).
// ---------------------------------------------------------------------------
__global__ __launch_bounds__(256, 2) void attn_kernel(
    const float* __restrict__ states, const short* __restrict__ awt_hi,
    const short* __restrict__ awt_lo, const float* __restrict__ att_v,
    const float* __restrict__ att_b, float* __restrict__ feats) {
  __shared__ __align__(16) float st_s[16][132];
  __shared__ __align__(16) short ah_s[16][132];
  __shared__ __align__(16) short al_s[16][132];
  __shared__ float spart[4][16];
  __shared__ float score_s[16];
  __shared__ float cm[128], cl[128], ca[128];

  int bid = blockIdx.x, tid = threadIdx.x;
  int b, dir, S, featOff; const float* stb;
  if (bid < 256) {
    b = bid >> 1; dir = bid & 1; S = SC_;
    stb = states + (dir ? SZ_ST_CTX : 0) + (size_t)b * SC_ * C_;
    featOff = dir * 128;
  } else {
    int q = bid - 256; b = q >> 1; dir = q & 1; S = SE_;
    stb = states + 2*SZ_ST_CTX + (dir ? SZ_ST_END : 0) + (size_t)b * SE_ * C_;
    featOff = 256 + dir * 128;
  }

  int w = tid >> 6, lane = tid & 63;
  int quad = lane >> 4, l15 = lane & 15;

  // B-frags: wave w covers d = [32w, 32w+32); frag = awt[d][k] (= att_w[k][d])
  int d0 = 32 * w + l15, d1 = d0 + 16;
  bf16x8 bh0[4], bh1[4], bl0[4], bl1[4];
#pragma unroll
  for (int kt = 0; kt < 4; ++kt) {
    bh0[kt] = *(const bf16x8*)&awt_hi[d0*128 + kt*32 + quad*8];
    bh1[kt] = *(const bf16x8*)&awt_hi[d1*128 + kt*32 + quad*8];
    bl0[kt] = *(const bf16x8*)&awt_lo[d0*128 + kt*32 + quad*8];
    bl1[kt] = *(const bf16x8*)&awt_lo[d1*128 + kt*32 + quad*8];
  }
  float vv0 = att_v[d0], vv1 = att_v[d1];
  float bb0 = att_b[d0], bb1 = att_b[d1];

  int c = tid & 127, half = tid >> 7;
  float m = -1e30f, lsum = 0.f, acc = 0.f;

  // chunk staging coords: row = tid>>4, cols (tid&15)*8..+8
  int lrow = tid >> 4, lcol = (tid & 15) * 8;
  float4 p0, p1;
  {
    const float* src = stb + (size_t)lrow * C_ + lcol;
    p0 = *(const float4*)(src);
    p1 = *(const float4*)(src + 4);
  }

  int nchunks = S >> 4;
  for (int ch = 0; ch < nchunks; ++ch) {
    __syncthreads();   // B0: prior chunk's LDS readers done
    float f[8] = {p0.x, p0.y, p0.z, p0.w, p1.x, p1.y, p1.z, p1.w};
    short hi8[8], lo8[8];
#pragma unroll
    for (int j = 0; j < 8; ++j) {
      unsigned short h = f2bf_rne(f[j]);
      float hf = __uint_as_float((unsigned)h << 16);
      hi8[j] = (short)h;
      lo8[j] = (short)f2bf_rne(f[j] - hf);
    }
    *(float4*)(&st_s[lrow][lcol])     = p0;
    *(float4*)(&st_s[lrow][lcol + 4]) = p1;
    *(bf16x8*)(&ah_s[lrow][lcol]) = *(bf16x8*)hi8;
    *(bf16x8*)(&al_s[lrow][lcol]) = *(bf16x8*)lo8;
    if (ch + 1 < nchunks) {   // prefetch next chunk (in flight across compute)
      const float* src = stb + (size_t)((ch + 1) * 16 + lrow) * C_ + lcol;
      p0 = *(const float4*)(src);
      p1 = *(const float4*)(src + 4);
    }
    __syncthreads();   // B1: staging visible

    // T = chunk @ att_w  (bf16x3 MFMA)
    f32x4 ac0 = {0.f, 0.f, 0.f, 0.f}, ac1 = {0.f, 0.f, 0.f, 0.f};
#pragma unroll
    for (int kt = 0; kt < 4; ++kt) {
      bf16x8 a_hi = *(bf16x8*)&ah_s[l15][kt*32 + quad*8];
      bf16x8 a_lo = *(bf16x8*)&al_s[l15][kt*32 + quad*8];
      ac0 = __builtin_amdgcn_mfma_f32_16x16x32_bf16(a_hi, bh0[kt], ac0, 0, 0, 0);
      ac0 = __builtin_amdgcn_mfma_f32_16x16x32_bf16(a_hi, bl0[kt], ac0, 0, 0, 0);
      ac0 = __builtin_amdgcn_mfma_f32_16x16x32_bf16(a_lo, bh0[kt], ac0, 0, 0, 0);
      ac1 = __builtin_amdgcn_mfma_f32_16x16x32_bf16(a_hi, bh1[kt], ac1, 0, 0, 0);
      ac1 = __builtin_amdgcn_mfma_f32_16x16x32_bf16(a_hi, bl1[kt], ac1, 0, 0, 0);
      ac1 = __builtin_amdgcn_mfma_f32_16x16x32_bf16(a_lo, bh1[kt], ac1, 0, 0, 0);
    }

    // epilogue: rows quad*4+r, per-lane d pair -> partial score; quad reduce
    float part[4];
#pragma unroll
    for (int r = 0; r < 4; ++r)
      part[r] = fast_tanh(ac0[r] + bb0) * vv0 + fast_tanh(ac1[r] + bb1) * vv1;
#pragma unroll
    for (int mask = 1; mask <= 8; mask <<= 1)
#pragma unroll
      for (int r = 0; r < 4; ++r)
        part[r] += __shfl_xor(part[r], mask, 64);
    if (l15 == 0) {
#pragma unroll
      for (int r = 0; r < 4; ++r) spart[w][quad*4 + r] = part[r];
    }
    __syncthreads();   // B2: spart visible
    if (tid < 16)
      score_s[tid] = spart[0][tid] + spart[1][tid] + spart[2][tid] + spart[3][tid];
    __syncthreads();   // B3: scores visible

    // online softmax: half processes rows half*8..+8, channel c
    float srow[8]; float smax = m;
#pragma unroll
    for (int r = 0; r < 8; ++r) { srow[r] = score_s[half*8 + r]; smax = fmaxf(smax, srow[r]); }
    float scale = __expf(m - smax);
    acc *= scale; lsum *= scale; m = smax;
#pragma unroll
    for (int r = 0; r < 8; ++r) {
      float wgt = __expf(srow[r] - m);
      lsum += wgt;
      acc += wgt * st_s[half*8 + r][c];
    }
  }

  __syncthreads();
  if (half == 1) { cm[c] = m; cl[c] = lsum; ca[c] = acc; }
  __syncthreads();
  if (half == 0) {
    float m1 = cm[c], l1 = cl[c], a1 = ca[c];
    float M = fmaxf(m, m1);
    float w0 = __expf(m - M), w1 = __expf(m1 - M);
    feats[b * 512 + featOff + c] = (acc * w0 + a1 * w1) / (lsum * w0 + l1 * w1);
  }
}

// ---------------------------------------------------------------------------
// Head
// ---------------------------------------------------------------------------
__global__ __launch_bounds__(128) void head_kernel(
    const float* __restrict__ feats, const float* __restrict__ hid_w,
    const float* __restrict__ hid_b, const float* __restrict__ out_w,
    const float* __restrict__ out_b, float* __restrict__ out) {
  __shared__ __align__(16) float f_s[512];
  __shared__ float part[2];
  int b = blockIdx.x, tid = threadIdx.x;
  for (int i = tid; i < 512; i += 128) f_s[i] = feats[b * 512 + i];
  __syncthreads();
  float h = hid_b[tid];
  for (int k = 0; k < 512; ++k) h += f_s[k] * hid_w[k * 128 + tid];
  h = fmaxf(h, 0.f);
  float p = h * out_w[tid];
#pragma unroll
  for (int off = 32; off > 0; off >>= 1) p += __shfl_xor(p, off, 64);
  if ((tid & 63) == 0) part[tid >> 6] = p;
  __syncthreads();
  if (tid == 0) out[b] = part[0] + part[1] + out_b[0];
}

// ---------------------------------------------------------------------------
extern "C" void kernel_launch(void* const* d_in, const int* in_sizes, int n_in,
                              void* d_out, int out_size, void* d_ws, size_t ws_size,
                              hipStream_t stream) {
  const int*   ctx     = (const int*)d_in[0];
  const int*   endseq  = (const int*)d_in[1];
  const int*   ctx_len = (const int*)d_in[2];
  const int*   end_len = (const int*)d_in[3];
  const float* emb     = (const float*)d_in[4];
  const float* fw_gw   = (const float*)d_in[5];
  const float* fw_gb   = (const float*)d_in[6];
  const float* fw_cw   = (const float*)d_in[7];
  const float* fw_cb   = (const float*)d_in[8];
  const float* bw_gw   = (const float*)d_in[9];
  const float* bw_gb   = (const float*)d_in[10];
  const float* bw_cw   = (const float*)d_in[11];
  const float* bw_cb   = (const float*)d_in[12];
  const float* att_v   = (const float*)d_in[13];
  const float* att_w   = (const float*)d_in[14];
  const float* att_b   = (const float*)d_in[15];
  const float* hid_w   = (const float*)d_in[16];
  const float* hid_b   = (const float*)d_in[17];
  const float* out_w   = (const float*)d_in[18];
  const float* out_b   = (const float*)d_in[19];
  float* ws  = (float*)d_ws;
  float* out = (float*)d_out;

  short* Ahi    = (short*)(ws + OFF_ST);
  short* Alo    = Ahi + (size_t)V_ * KP;
  short* Bthi   = (short*)(ws + OFF_BT);
  short* Btlo   = Bthi + (size_t)NCOL * KP;
  short* awt_hi = (short*)(ws + OFF_AWT);
  short* awt_lo = awt_hi + 128 * 128;

  pack_kernel<<<1299, 256, 0, stream>>>(fw_gw, fw_gb, fw_cw, fw_cb,
                                        bw_gw, bw_gb, bw_cw, bw_cb, ws);
  pack_bt<<<(NCOL * KP + 128 * 128 + 255) / 256, 256, 0, stream>>>(
      ws + OFF_WXP, Bthi, Btlo, att_w, awt_hi, awt_lo);
  pack_emb<<<(int)(((size_t)V_ * KP + 255) / 256), 256, 0, stream>>>(emb, Ahi, Alo);

  dim3 ggrid(6, 391);
  gemm_mfma<<<ggrid, 256, 0, stream>>>(Ahi, Alo, Bthi, Btlo, ws + OFF_PROJ);

  recur_pair_kernel<<<256, 256, 0, stream>>>(ctx, endseq, ctx_len, end_len,
                                             ws + OFF_PROJ, ws + OFF_UALL,
                                             ws + OFF_BIAS, ws + OFF_ST);

  attn_kernel<<<512, 256, 0, stream>>>(ws + OFF_ST, awt_hi, awt_lo,
                                       att_v, att_b, ws + OFF_FEATS);

  head_kernel<<<128, 128, 0, stream>>>(ws + OFF_FEATS, hid_w, hid_b,
                                       out_w, out_b, out);
}

// Round 3
// 851.131 us; speedup vs baseline: 1.2551x; 1.2551x over previous
//
#include <hip/hip_runtime.h>
#include <cstdint>
#include <cmath>

// Problem constants
static constexpr int V_  = 50000;
static constexpr int E_  = 300;
static constexpr int C_  = 128;
static constexpr int B_  = 128;
static constexpr int SC_ = 512;
static constexpr int SE_ = 64;
static constexpr int NCOL = 768;   // [fw_gate 256 | fw_cand 128 | bw_gate 256 | bw_cand 128]
static constexpr int KP  = 320;    // K padded to 10 x 32 for MFMA

// ws layout (float offsets)
static constexpr size_t OFF_PROJ  = 0;
static constexpr size_t SZ_PROJ   = (size_t)V_ * NCOL;
static constexpr size_t OFF_WXP   = OFF_PROJ + SZ_PROJ;
static constexpr size_t SZ_WXP    = (size_t)304 * NCOL;
static constexpr size_t OFF_UALL  = OFF_WXP + SZ_WXP;
static constexpr size_t SZ_UALL   = (size_t)C_ * NCOL;
static constexpr size_t OFF_BIAS  = OFF_UALL + SZ_UALL;
static constexpr size_t SZ_BIAS   = NCOL;
static constexpr size_t OFF_ST    = OFF_BIAS + SZ_BIAS;
static constexpr size_t SZ_ST_CTX = (size_t)B_ * SC_ * C_;
static constexpr size_t SZ_ST_END = (size_t)B_ * SE_ * C_;
static constexpr size_t SZ_ST     = 2*SZ_ST_CTX + 2*SZ_ST_END;    // 75.5 MB
static constexpr size_t OFF_FEATS = OFF_ST + SZ_ST;
static constexpr size_t SZ_FEATS  = (size_t)B_ * 512;
static constexpr size_t OFF_BT    = OFF_FEATS + SZ_FEATS;
static constexpr size_t SZ_BT     = (size_t)NCOL * KP / 2 * 2;    // 2 short arrays
static constexpr size_t OFF_AWT   = OFF_BT + SZ_BT;               // att_w^T hi/lo shorts (32768 shorts)
static constexpr size_t OFF_WPK   = OFF_AWT + 16384;              // packed recur weights
static constexpr size_t SZ_WPK    = 98304;                        // 2*256*128 + 2*256*64 floats
// A_hi/A_lo (bf16) OVERLAP the states region (dead once gemm ends; recur
// zeroes its own tail rows so no global memset is needed).

typedef __attribute__((ext_vector_type(8))) short bf16x8;
typedef __attribute__((ext_vector_type(4))) float f32x4;

static __device__ __forceinline__ unsigned short f2bf_rne(float f) {
  unsigned u = __float_as_uint(f);
  unsigned r = u + 0x7fffu + ((u >> 16) & 1u);
  return (unsigned short)(r >> 16);
}

static __device__ __forceinline__ void gload_lds16(const short* g, short* l) {
  __builtin_amdgcn_global_load_lds(
      (const __attribute__((address_space(1))) void*)g,
      (__attribute__((address_space(3))) void*)l, 16, 0, 0);
}

// fast activations: __expf + v_rcp_f32 (~1e-6 rel err; logit threshold 7.4e-5)
static __device__ __forceinline__ float fast_sigmoid(float x) {
  return __builtin_amdgcn_rcpf(1.f + __expf(-x));
}
static __device__ __forceinline__ float fast_tanh(float x) {
  return fmaf(-2.f, __builtin_amdgcn_rcpf(__expf(2.f * x) + 1.f), 1.f);
}

// ---------------------------------------------------------------------------
// Pack: Wxp[304][768] fp32, Uall[128][768], bias[768]
// ---------------------------------------------------------------------------
__global__ void pack_kernel(const float* __restrict__ fw_gw, const float* __restrict__ fw_gb,
                            const float* __restrict__ fw_cw, const float* __restrict__ fw_cb,
                            const float* __restrict__ bw_gw, const float* __restrict__ bw_gb,
                            const float* __restrict__ bw_cw, const float* __restrict__ bw_cb,
                            float* __restrict__ ws) {
  int i = blockIdx.x * 256 + threadIdx.x;
  float* Wxp  = ws + OFF_WXP;
  float* Uall = ws + OFF_UALL;
  float* bias = ws + OFF_BIAS;
  if (i < 304 * NCOL) {
    int k = i / NCOL, c = i % NCOL;
    float v = 0.f;
    if (k < 300) {
      if (c < 256)      v = fw_gw[k*256 + c];
      else if (c < 384) v = fw_cw[k*128 + (c-256)];
      else if (c < 640) v = bw_gw[k*256 + (c-384)];
      else              v = bw_cw[k*128 + (c-640)];
    }
    Wxp[i] = v;
    return;
  }
  int j = i - 304 * NCOL;
  if (j >= 0 && j < 128 * NCOL) {
    int k = j / NCOL, c = j % NCOL;
    int kk = 300 + k;
    float v;
    if (c < 256)      v = fw_gw[kk*256 + c];
    else if (c < 384) v = fw_cw[kk*128 + (c-256)];
    else if (c < 640) v = bw_gw[kk*256 + (c-384)];
    else              v = bw_cw[kk*128 + (c-640)];
    Uall[j] = v;
    return;
  }
  int m = j - 128 * NCOL;
  if (m >= 0 && m < NCOL) {
    float v;
    if (m < 256)      v = fw_gb[m];
    else if (m < 384) v = fw_cb[m-256];
    else if (m < 640) v = bw_gb[m-384];
    else              v = bw_cb[m-640];
    bias[m] = v;
  }
}

// Packed recurrence weights: per-thread-contiguous blocks.
// wgpack[dir][t][kk]: kk = kl*2+cp; k = (t&1)*64+kl; col = (t&~1)|cp
// wcpack[dir][t][kl]: k = (t&1)*64+kl; c = t>>1
__global__ void pack_w2(const float* __restrict__ fw_gw, const float* __restrict__ bw_gw,
                        const float* __restrict__ fw_cw, const float* __restrict__ bw_cw,
                        float* __restrict__ wpack) {
  int i = blockIdx.x * 256 + threadIdx.x;
  if (i < 65536) {
    int d = i >> 15, r = i & 32767;
    int t = r >> 7, kk = r & 127;
    int kl = kk >> 1, cp = kk & 1;
    int k = (t & 1) * 64 + kl;
    int col = (t & ~1) | cp;
    const float* gw = d ? bw_gw : fw_gw;
    wpack[i] = gw[(300 + k) * 256 + col];
    return;
  }
  int j = i - 65536;
  if (j < 32768) {
    int d = j >> 14, r = j & 16383;
    int t = r >> 6, kl = r & 63;
    int k = (t & 1) * 64 + kl;
    int cc = t >> 1;
    const float* cw = d ? bw_cw : fw_cw;
    wpack[65536 + j] = cw[(300 + k) * 128 + cc];
  }
}

// Bt hi/lo for the proj GEMM + att_w^T hi/lo for the MFMA attention
__global__ void pack_bt(const float* __restrict__ Wxp, short* __restrict__ Bthi,
                        short* __restrict__ Btlo, const float* __restrict__ att_w,
                        short* __restrict__ awt_hi, short* __restrict__ awt_lo) {
  int i = blockIdx.x * 256 + threadIdx.x;
  if (i < NCOL * KP) {
    int k = i % KP, n = i / KP;
    float v = (k < 304) ? Wxp[(size_t)k * NCOL + n] : 0.f;
    unsigned short h = f2bf_rne(v);
    float hf = __uint_as_float((unsigned)h << 16);
    unsigned short lo = f2bf_rne(v - hf);
    Bthi[i] = (short)h;
    Btlo[i] = (short)lo;
    return;
  }
  int j = i - NCOL * KP;
  if (j < 128 * 128) {
    int d = j >> 7, c = j & 127;
    float v = att_w[(size_t)c * 128 + d];   // transpose: awt[d][k=c]
    unsigned short h = f2bf_rne(v);
    float hf = __uint_as_float((unsigned)h << 16);
    unsigned short lo = f2bf_rne(v - hf);
    awt_hi[j] = (short)h;
    awt_lo[j] = (short)lo;
  }
}

__global__ void pack_emb(const float* __restrict__ emb, short* __restrict__ Ahi,
                         short* __restrict__ Alo) {
  size_t i = (size_t)blockIdx.x * 256 + threadIdx.x;
  if (i >= (size_t)V_ * KP) return;
  int k = (int)(i % KP);
  size_t row = i / KP;
  float v = (k < E_) ? emb[row * E_ + k] : 0.f;
  unsigned short h = f2bf_rne(v);
  float hf = __uint_as_float((unsigned)h << 16);
  unsigned short lo = f2bf_rne(v - hf);
  Ahi[i] = (short)h;
  Alo[i] = (short)lo;
}

// ---------------------------------------------------------------------------
// proj = emb @ Wxp via bf16x3 split MFMA (m97 structure)
// ---------------------------------------------------------------------------
__global__ __launch_bounds__(256) void gemm_mfma(
    const short* __restrict__ Ahi, const short* __restrict__ Alo,
    const short* __restrict__ Bthi, const short* __restrict__ Btlo,
    float* __restrict__ proj) {
  __shared__ short lds[16384];
  int tid = threadIdx.x, wid = tid >> 6, lane = tid & 63;
  int n0 = blockIdx.x * 128, m0 = blockIdx.y * 128;
  f32x4 acc[4][4] = {};

  int lr = lane >> 2, lc = lane & 3;
  int q0 = wid * 2, q1 = q0 + 1;
  int r0 = q0 * 16 + lr, r1 = q1 * 16 + lr;
  int am0 = m0 + r0; if (am0 > V_ - 1) am0 = V_ - 1;
  int am1 = m0 + r1; if (am1 > V_ - 1) am1 = V_ - 1;
  size_t gaOff0 = (size_t)am0 * KP + lc * 8;
  size_t gaOff1 = (size_t)am1 * KP + lc * 8;
  size_t gbOff0 = (size_t)(n0 + r0) * KP + lc * 8;
  size_t gbOff1 = (size_t)(n0 + r1) * KP + lc * 8;

  int quad = lane >> 4;
  int arow = (wid >> 1) * 64 + (lane & 15);
  int brow = (wid & 1) * 64 + (lane & 15);

  for (int k0 = 0; k0 < KP; k0 += 32) {
    gload_lds16(Ahi  + gaOff0 + k0, lds +         q0 * 512);
    gload_lds16(Ahi  + gaOff1 + k0, lds +         q1 * 512);
    gload_lds16(Alo  + gaOff0 + k0, lds +  4096 + q0 * 512);
    gload_lds16(Alo  + gaOff1 + k0, lds +  4096 + q1 * 512);
    gload_lds16(Bthi + gbOff0 + k0, lds +  8192 + q0 * 512);
    gload_lds16(Bthi + gbOff1 + k0, lds +  8192 + q1 * 512);
    gload_lds16(Btlo + gbOff0 + k0, lds + 12288 + q0 * 512);
    gload_lds16(Btlo + gbOff1 + k0, lds + 12288 + q1 * 512);
    __syncthreads();

    bf16x8 ah[4], al[4], bh[4], bl[4];
#pragma unroll
    for (int i = 0; i < 4; ++i) {
      ah[i] = *(bf16x8*)&lds[        (arow + i*16) * 32 + quad * 8];
      al[i] = *(bf16x8*)&lds[ 4096 + (arow + i*16) * 32 + quad * 8];
      bh[i] = *(bf16x8*)&lds[ 8192 + (brow + i*16) * 32 + quad * 8];
      bl[i] = *(bf16x8*)&lds[12288 + (brow + i*16) * 32 + quad * 8];
    }
#pragma unroll
    for (int i = 0; i < 4; ++i)
#pragma unroll
      for (int j = 0; j < 4; ++j) {
        acc[i][j] = __builtin_amdgcn_mfma_f32_16x16x32_bf16(ah[i], bh[j], acc[i][j], 0, 0, 0);
        acc[i][j] = __builtin_amdgcn_mfma_f32_16x16x32_bf16(ah[i], bl[j], acc[i][j], 0, 0, 0);
        acc[i][j] = __builtin_amdgcn_mfma_f32_16x16x32_bf16(al[i], bh[j], acc[i][j], 0, 0, 0);
      }
    __syncthreads();
  }

  int colb = n0 + (wid & 1) * 64 + (lane & 15);
  int rowb = m0 + (wid >> 1) * 64 + quad * 4;
#pragma unroll
  for (int i = 0; i < 4; ++i) {
    int rb = rowb + i * 16;
#pragma unroll
    for (int j = 0; j < 4; ++j) {
      int cc = colb + j * 16;
#pragma unroll
      for (int r = 0; r < 4; ++r) {
        int rr = rb + r;
        if (rr < V_) proj[(size_t)rr * NCOL + cc] = acc[i][j][r];
      }
    }
  }
}

// ---------------------------------------------------------------------------
// Recurrence v3 (2-barrier, shuffle-reduce): chain-per-WG, 512 WGs, 2 WG/CU.
// k-split lives inside a lane PAIR (kh = tid&1), so both matvec reductions
// are a single shfl_xor(.,1) instead of an LDS-partials round-trip + barrier.
// Gate: thread t -> partial for cols {t&~1, t|1} over its 64-k half.
// Cand: col c = t>>1 split across the pair. Only 2 barriers/step remain:
// B1 (rh/u published), B2 (h updated). Weights preloaded per-thread
// contiguous (pack_w2), same register behavior as the 466us round-0 kernel.
// ---------------------------------------------------------------------------
__global__ __attribute__((amdgpu_flat_work_group_size(256, 256),
                          amdgpu_waves_per_eu(2, 2)))
void recur2_kernel(
    const int* __restrict__ ctx, const int* __restrict__ endseq,
    const int* __restrict__ ctx_len, const int* __restrict__ end_len,
    const float* __restrict__ proj, const float* __restrict__ wpack,
    const float* __restrict__ bias, float* __restrict__ states) {
  __shared__ __align__(16) float h_s[128];
  __shared__ __align__(16) float rh_s[128];
  __shared__ float u_s[128];

  int bid = blockIdx.x, tid = threadIdx.x;
  const int* seq; int S, L, b, dir; float* stbase;
  if (bid < 256) {
    b = bid >> 1; dir = bid & 1;
    seq = ctx + b * SC_; S = SC_; L = ctx_len[b];
    stbase = states + (dir ? SZ_ST_CTX : 0) + (size_t)b * SC_ * C_;
  } else {
    int q = bid - 256; b = q >> 1; dir = q & 1;
    seq = endseq + b * SE_; S = SE_; L = end_len[b];
    stbase = states + 2*SZ_ST_CTX + (dir ? SZ_ST_END : 0) + (size_t)b * SE_ * C_;
  }
  int dirOff = dir ? 384 : 0;
  int c = tid >> 1, kh = tid & 1;
  int hbase = kh * 16;   // float4 index of this thread's 64-k half

  // preload packed weights (contiguous per thread): 32+16 float4
  float4 wgt[32], wct[16];
  {
    const float4* wgp = (const float4*)(wpack + ((size_t)dir * 256 + tid) * 128);
    const float4* wcp = (const float4*)(wpack + 65536 + ((size_t)dir * 256 + tid) * 64);
#pragma unroll
    for (int i = 0; i < 32; ++i) wgt[i] = wgp[i];
#pragma unroll
    for (int i = 0; i < 16; ++i) wct[i] = wcp[i];
  }
  float bias_g = bias[dirOff + tid];
  float bias_c = bias[dirOff + 256 + c];

  if (tid < 128) h_s[tid] = 0.f;
  __syncthreads();

  int pos0 = dir ? (L - 1) : 0;
  const float* xr0 = proj + (size_t)seq[pos0] * NCOL + dirOff;
  float xg = xr0[tid];
  float xc = xr0[256 + c];

  for (int t = 0; t < L; ++t) {
    // prefetch next-step x row (latency spans the whole step)
    float xg_n = 0.f, xc_n = 0.f;
    if (t + 1 < L) {
      int pos_n = dir ? (L - 2 - t) : (t + 1);
      const float* xr = proj + (size_t)seq[pos_n] * NCOL + dirOff;
      xg_n = xr[tid];
      xc_n = xr[256 + c];
    }

    // gate partials: cols {tid&~1, tid|1} over k-half kh
    float a0 = 0.f, a1 = 0.f, a2 = 0.f, a3 = 0.f;
    const float4* h4 = (const float4*)h_s;
#pragma unroll
    for (int i = 0; i < 16; ++i) {
      float4 hv = h4[hbase + i];
      float4 w0 = wgt[2*i], w1 = wgt[2*i + 1];
      a0 = fmaf(hv.x, w0.x, a0); a1 = fmaf(hv.x, w0.y, a1);
      a2 = fmaf(hv.y, w0.z, a2); a3 = fmaf(hv.y, w0.w, a3);
      a0 = fmaf(hv.z, w1.x, a0); a1 = fmaf(hv.z, w1.y, a1);
      a2 = fmaf(hv.w, w1.z, a2); a3 = fmaf(hv.w, w1.w, a3);
    }
    float pa0 = a0 + a2, pa1 = a1 + a3;
    float g0 = pa0 + __shfl_xor(pa0, 1, 64);   // full col t&~1
    float g1 = pa1 + __shfl_xor(pa1, 1, 64);   // full col t|1
    float g = fast_sigmoid(((tid & 1) ? g1 : g0) + xg + bias_g);

    if (tid < 128) rh_s[tid] = g * h_s[tid];
    else           u_s[tid - 128] = g;
    __syncthreads();   // B1: rh/u visible

    // cand: col c = tid>>1 over k-half kh
    float c0 = 0.f, c1 = 0.f, c2 = 0.f, c3 = 0.f;
    const float4* rh4 = (const float4*)rh_s;
#pragma unroll
    for (int i = 0; i < 16; ++i) {
      float4 rv = rh4[hbase + i];
      float4 w = wct[i];
      c0 = fmaf(rv.x, w.x, c0); c1 = fmaf(rv.y, w.y, c1);
      c2 = fmaf(rv.z, w.z, c2); c3 = fmaf(rv.w, w.w, c3);
    }
    float ac = (c0 + c1) + (c2 + c3);
    ac += __shfl_xor(ac, 1, 64);
    float cd = fast_tanh(ac + xc + bias_c);
    float u  = u_s[c];
    float ho = h_s[c];        // pair reads before even-lane write (lockstep)
    float hn = u * ho + (1.f - u) * cd;
    if (!kh) {
      h_s[c] = hn;
      int pos = dir ? (L - 1 - t) : t;
      stbase[(size_t)pos * C_ + c] = hn;
    }
    __syncthreads();   // B2: h visible for next step's gate
    xg = xg_n; xc = xc_n;
  }

  for (int i = L * C_ + tid; i < S * C_; i += 256) stbase[i] = 0.f;
}

// ---------------------------------------------------------------------------
// Attention v2: MFMA bf16x3 score projection. Per WG (b, dir, arr):
// B-frags = att_w^T hi/lo in registers (wave w owns d-cols [32w,+32)).
// Chunks of 16 state rows: stage fp32 + bf16 hi/lo to LDS (1-chunk register
// prefetch), 24 mfma/wave, epilogue tanh*v + quad-shfl + spart reduce,
// online softmax (half = rows 0-7 / 8-15; halves merged at end).
// ---------------------------------------------------------------------------
__global__ __launch_bounds__(256, 2) void attn_kernel(
    const float* __restrict__ states, const short* __restrict__ awt_hi,
    const short* __restrict__ awt_lo, const float* __restrict__ att_v,
    const float* __restrict__ att_b, float* __restrict__ feats) {
  __shared__ __align__(16) float st_s[16][132];
  __shared__ __align__(16) short ah_s[16][132];
  __shared__ __align__(16) short al_s[16][132];
  __shared__ float spart[4][16];
  __shared__ float score_s[16];
  __shared__ float cm[128], cl[128], ca[128];

  int bid = blockIdx.x, tid = threadIdx.x;
  int b, dir, S, featOff; const float* stb;
  if (bid < 256) {
    b = bid >> 1; dir = bid & 1; S = SC_;
    stb = states + (dir ? SZ_ST_CTX : 0) + (size_t)b * SC_ * C_;
    featOff = dir * 128;
  } else {
    int q = bid - 256; b = q >> 1; dir = q & 1; S = SE_;
    stb = states + 2*SZ_ST_CTX + (dir ? SZ_ST_END : 0) + (size_t)b * SE_ * C_;
    featOff = 256 + dir * 128;
  }

  int w = tid >> 6, lane = tid & 63;
  int quad = lane >> 4, l15 = lane & 15;

  // B-frags: wave w covers d = [32w, 32w+32); frag = awt[d][k] (= att_w[k][d])
  int d0 = 32 * w + l15, d1 = d0 + 16;
  bf16x8 bh0[4], bh1[4], bl0[4], bl1[4];
#pragma unroll
  for (int kt = 0; kt < 4; ++kt) {
    bh0[kt] = *(const bf16x8*)&awt_hi[d0*128 + kt*32 + quad*8];
    bh1[kt] = *(const bf16x8*)&awt_hi[d1*128 + kt*32 + quad*8];
    bl0[kt] = *(const bf16x8*)&awt_lo[d0*128 + kt*32 + quad*8];
    bl1[kt] = *(const bf16x8*)&awt_lo[d1*128 + kt*32 + quad*8];
  }
  float vv0 = att_v[d0], vv1 = att_v[d1];
  float bb0 = att_b[d0], bb1 = att_b[d1];

  int c = tid & 127, half = tid >> 7;
  float m = -1e30f, lsum = 0.f, acc = 0.f;

  // chunk staging coords: row = tid>>4, cols (tid&15)*8..+8
  int lrow = tid >> 4, lcol = (tid & 15) * 8;
  float4 p0, p1;
  {
    const float* src = stb + (size_t)lrow * C_ + lcol;
    p0 = *(const float4*)(src);
    p1 = *(const float4*)(src + 4);
  }

  int nchunks = S >> 4;
  for (int ch = 0; ch < nchunks; ++ch) {
    __syncthreads();   // B0: prior chunk's LDS readers done
    float f[8] = {p0.x, p0.y, p0.z, p0.w, p1.x, p1.y, p1.z, p1.w};
    short hi8[8], lo8[8];
#pragma unroll
    for (int j = 0; j < 8; ++j) {
      unsigned short h = f2bf_rne(f[j]);
      float hf = __uint_as_float((unsigned)h << 16);
      hi8[j] = (short)h;
      lo8[j] = (short)f2bf_rne(f[j] - hf);
    }
    *(float4*)(&st_s[lrow][lcol])     = p0;
    *(float4*)(&st_s[lrow][lcol + 4]) = p1;
    *(bf16x8*)(&ah_s[lrow][lcol]) = *(bf16x8*)hi8;
    *(bf16x8*)(&al_s[lrow][lcol]) = *(bf16x8*)lo8;
    if (ch + 1 < nchunks) {   // prefetch next chunk (in flight across compute)
      const float* src = stb + (size_t)((ch + 1) * 16 + lrow) * C_ + lcol;
      p0 = *(const float4*)(src);
      p1 = *(const float4*)(src + 4);
    }
    __syncthreads();   // B1: staging visible

    // T = chunk @ att_w  (bf16x3 MFMA)
    f32x4 ac0 = {0.f, 0.f, 0.f, 0.f}, ac1 = {0.f, 0.f, 0.f, 0.f};
#pragma unroll
    for (int kt = 0; kt < 4; ++kt) {
      bf16x8 a_hi = *(bf16x8*)&ah_s[l15][kt*32 + quad*8];
      bf16x8 a_lo = *(bf16x8*)&al_s[l15][kt*32 + quad*8];
      ac0 = __builtin_amdgcn_mfma_f32_16x16x32_bf16(a_hi, bh0[kt], ac0, 0, 0, 0);
      ac0 = __builtin_amdgcn_mfma_f32_16x16x32_bf16(a_hi, bl0[kt], ac0, 0, 0, 0);
      ac0 = __builtin_amdgcn_mfma_f32_16x16x32_bf16(a_lo, bh0[kt], ac0, 0, 0, 0);
      ac1 = __builtin_amdgcn_mfma_f32_16x16x32_bf16(a_hi, bh1[kt], ac1, 0, 0, 0);
      ac1 = __builtin_amdgcn_mfma_f32_16x16x32_bf16(a_hi, bl1[kt], ac1, 0, 0, 0);
      ac1 = __builtin_amdgcn_mfma_f32_16x16x32_bf16(a_lo, bh1[kt], ac1, 0, 0, 0);
    }

    // epilogue: rows quad*4+r, per-lane d pair -> partial score; quad reduce
    float part[4];
#pragma unroll
    for (int r = 0; r < 4; ++r)
      part[r] = fast_tanh(ac0[r] + bb0) * vv0 + fast_tanh(ac1[r] + bb1) * vv1;
#pragma unroll
    for (int mask = 1; mask <= 8; mask <<= 1)
#pragma unroll
      for (int r = 0; r < 4; ++r)
        part[r] += __shfl_xor(part[r], mask, 64);
    if (l15 == 0) {
#pragma unroll
      for (int r = 0; r < 4; ++r) spart[w][quad*4 + r] = part[r];
    }
    __syncthreads();   // B2: spart visible
    if (tid < 16)
      score_s[tid] = spart[0][tid] + spart[1][tid] + spart[2][tid] + spart[3][tid];
    __syncthreads();   // B3: scores visible

    // online softmax: half processes rows half*8..+8, channel c
    float srow[8]; float smax = m;
#pragma unroll
    for (int r = 0; r < 8; ++r) { srow[r] = score_s[half*8 + r]; smax = fmaxf(smax, srow[r]); }
    float scale = __expf(m - smax);
    acc *= scale; lsum *= scale; m = smax;
#pragma unroll
    for (int r = 0; r < 8; ++r) {
      float wgt = __expf(srow[r] - m);
      lsum += wgt;
      acc += wgt * st_s[half*8 + r][c];
    }
  }

  __syncthreads();
  if (half == 1) { cm[c] = m; cl[c] = lsum; ca[c] = acc; }
  __syncthreads();
  if (half == 0) {
    float m1 = cm[c], l1 = cl[c], a1 = ca[c];
    float M = fmaxf(m, m1);
    float w0 = __expf(m - M), w1 = __expf(m1 - M);
    feats[b * 512 + featOff + c] = (acc * w0 + a1 * w1) / (lsum * w0 + l1 * w1);
  }
}

// ---------------------------------------------------------------------------
// Head
// ---------------------------------------------------------------------------
__global__ __launch_bounds__(128) void head_kernel(
    const float* __restrict__ feats, const float* __restrict__ hid_w,
    const float* __restrict__ hid_b, const float* __restrict__ out_w,
    const float* __restrict__ out_b, float* __restrict__ out) {
  __shared__ __align__(16) float f_s[512];
  __shared__ float part[2];
  int b = blockIdx.x, tid = threadIdx.x;
  for (int i = tid; i < 512; i += 128) f_s[i] = feats[b * 512 + i];
  __syncthreads();
  float h = hid_b[tid];
  for (int k = 0; k < 512; ++k) h += f_s[k] * hid_w[k * 128 + tid];
  h = fmaxf(h, 0.f);
  float p = h * out_w[tid];
#pragma unroll
  for (int off = 32; off > 0; off >>= 1) p += __shfl_xor(p, off, 64);
  if ((tid & 63) == 0) part[tid >> 6] = p;
  __syncthreads();
  if (tid == 0) out[b] = part[0] + part[1] + out_b[0];
}

// ---------------------------------------------------------------------------
extern "C" void kernel_launch(void* const* d_in, const int* in_sizes, int n_in,
                              void* d_out, int out_size, void* d_ws, size_t ws_size,
                              hipStream_t stream) {
  const int*   ctx     = (const int*)d_in[0];
  const int*   endseq  = (const int*)d_in[1];
  const int*   ctx_len = (const int*)d_in[2];
  const int*   end_len = (const int*)d_in[3];
  const float* emb     = (const float*)d_in[4];
  const float* fw_gw   = (const float*)d_in[5];
  const float* fw_gb   = (const float*)d_in[6];
  const float* fw_cw   = (const float*)d_in[7];
  const float* fw_cb   = (const float*)d_in[8];
  const float* bw_gw   = (const float*)d_in[9];
  const float* bw_gb   = (const float*)d_in[10];
  const float* bw_cw   = (const float*)d_in[11];
  const float* bw_cb   = (const float*)d_in[12];
  const float* att_v   = (const float*)d_in[13];
  const float* att_w   = (const float*)d_in[14];
  const float* att_b   = (const float*)d_in[15];
  const float* hid_w   = (const float*)d_in[16];
  const float* hid_b   = (const float*)d_in[17];
  const float* out_w   = (const float*)d_in[18];
  const float* out_b   = (const float*)d_in[19];
  float* ws  = (float*)d_ws;
  float* out = (float*)d_out;

  short* Ahi    = (short*)(ws + OFF_ST);
  short* Alo    = Ahi + (size_t)V_ * KP;
  short* Bthi   = (short*)(ws + OFF_BT);
  short* Btlo   = Bthi + (size_t)NCOL * KP;
  short* awt_hi = (short*)(ws + OFF_AWT);
  short* awt_lo = awt_hi + 128 * 128;

  pack_kernel<<<1299, 256, 0, stream>>>(fw_gw, fw_gb, fw_cw, fw_cb,
                                        bw_gw, bw_gb, bw_cw, bw_cb, ws);
  pack_w2<<<384, 256, 0, stream>>>(fw_gw, bw_gw, fw_cw, bw_cw, ws + OFF_WPK);
  pack_bt<<<(NCOL * KP + 128 * 128 + 255) / 256, 256, 0, stream>>>(
      ws + OFF_WXP, Bthi, Btlo, att_w, awt_hi, awt_lo);
  pack_emb<<<(int)(((size_t)V_ * KP + 255) / 256), 256, 0, stream>>>(emb, Ahi, Alo);

  dim3 ggrid(6, 391);
  gemm_mfma<<<ggrid, 256, 0, stream>>>(Ahi, Alo, Bthi, Btlo, ws + OFF_PROJ);

  recur2_kernel<<<512, 256, 0, stream>>>(ctx, endseq, ctx_len, end_len,
                                         ws + OFF_PROJ, ws + OFF_WPK,
                                         ws + OFF_BIAS, ws + OFF_ST);

  attn_kernel<<<512, 256, 0, stream>>>(ws + OFF_ST, awt_hi, awt_lo,
                                       att_v, att_b, ws + OFF_FEATS);

  head_kernel<<<128, 128, 0, stream>>>(ws + OFF_FEATS, hid_w, hid_b,
                                       out_w, out_b, out);
}

// Round 4
// 768.426 us; speedup vs baseline: 1.3902x; 1.1076x over previous
//
#include <hip/hip_runtime.h>
#include <cstdint>
#include <cmath>

// Problem constants
static constexpr int V_  = 50000;
static constexpr int E_  = 300;
static constexpr int C_  = 128;
static constexpr int B_  = 128;
static constexpr int SC_ = 512;
static constexpr int SE_ = 64;
static constexpr int NCOL = 768;   // [fw_gate 256 | fw_cand 128 | bw_gate 256 | bw_cand 128]
static constexpr int KP  = 320;    // K padded to 10 x 32 for MFMA

// ws layout (float offsets)
static constexpr size_t OFF_PROJ  = 0;
static constexpr size_t SZ_PROJ   = (size_t)V_ * NCOL;
static constexpr size_t OFF_WXP   = OFF_PROJ + SZ_PROJ;
static constexpr size_t SZ_WXP    = (size_t)304 * NCOL;
static constexpr size_t OFF_UALL  = OFF_WXP + SZ_WXP;
static constexpr size_t SZ_UALL   = (size_t)C_ * NCOL;
static constexpr size_t OFF_BIAS  = OFF_UALL + SZ_UALL;
static constexpr size_t SZ_BIAS   = NCOL;
static constexpr size_t OFF_ST    = OFF_BIAS + SZ_BIAS;
static constexpr size_t SZ_ST_CTX = (size_t)B_ * SC_ * C_;
static constexpr size_t SZ_ST_END = (size_t)B_ * SE_ * C_;
static constexpr size_t SZ_ST     = 2*SZ_ST_CTX + 2*SZ_ST_END;    // 75.5 MB
static constexpr size_t OFF_FEATS = OFF_ST + SZ_ST;
static constexpr size_t SZ_FEATS  = (size_t)B_ * 512;
static constexpr size_t OFF_BT    = OFF_FEATS + SZ_FEATS;
static constexpr size_t SZ_BT     = (size_t)NCOL * KP / 2 * 2;    // 2 short arrays
static constexpr size_t OFF_AWT   = OFF_BT + SZ_BT;               // att_w^T hi/lo shorts
// A_hi/A_lo (bf16) OVERLAP the states region (dead once gemm ends; recur
// zeroes its own tail rows so no global memset is needed).

typedef __attribute__((ext_vector_type(8))) short bf16x8;
typedef __attribute__((ext_vector_type(4))) float f32x4;

static __device__ __forceinline__ unsigned short f2bf_rne(float f) {
  unsigned u = __float_as_uint(f);
  unsigned r = u + 0x7fffu + ((u >> 16) & 1u);
  return (unsigned short)(r >> 16);
}

static __device__ __forceinline__ void gload_lds16(const short* g, short* l) {
  __builtin_amdgcn_global_load_lds(
      (const __attribute__((address_space(1))) void*)g,
      (__attribute__((address_space(3))) void*)l, 16, 0, 0);
}

// fast activations: __expf + v_rcp_f32 (~1e-6 rel err; logit threshold 7.4e-5)
static __device__ __forceinline__ float fast_sigmoid(float x) {
  return __builtin_amdgcn_rcpf(1.f + __expf(-x));
}
static __device__ __forceinline__ float fast_tanh(float x) {
  return fmaf(-2.f, __builtin_amdgcn_rcpf(__expf(2.f * x) + 1.f), 1.f);
}

// ---------------------------------------------------------------------------
// Pack: Wxp[304][768] fp32, Uall[128][768], bias[768]
// ---------------------------------------------------------------------------
__global__ void pack_kernel(const float* __restrict__ fw_gw, const float* __restrict__ fw_gb,
                            const float* __restrict__ fw_cw, const float* __restrict__ fw_cb,
                            const float* __restrict__ bw_gw, const float* __restrict__ bw_gb,
                            const float* __restrict__ bw_cw, const float* __restrict__ bw_cb,
                            float* __restrict__ ws) {
  int i = blockIdx.x * 256 + threadIdx.x;
  float* Wxp  = ws + OFF_WXP;
  float* Uall = ws + OFF_UALL;
  float* bias = ws + OFF_BIAS;
  if (i < 304 * NCOL) {
    int k = i / NCOL, c = i % NCOL;
    float v = 0.f;
    if (k < 300) {
      if (c < 256)      v = fw_gw[k*256 + c];
      else if (c < 384) v = fw_cw[k*128 + (c-256)];
      else if (c < 640) v = bw_gw[k*256 + (c-384)];
      else              v = bw_cw[k*128 + (c-640)];
    }
    Wxp[i] = v;
    return;
  }
  int j = i - 304 * NCOL;
  if (j >= 0 && j < 128 * NCOL) {
    int k = j / NCOL, c = j % NCOL;
    int kk = 300 + k;
    float v;
    if (c < 256)      v = fw_gw[kk*256 + c];
    else if (c < 384) v = fw_cw[kk*128 + (c-256)];
    else if (c < 640) v = bw_gw[kk*256 + (c-384)];
    else              v = bw_cw[kk*128 + (c-640)];
    Uall[j] = v;
    return;
  }
  int m = j - 128 * NCOL;
  if (m >= 0 && m < NCOL) {
    float v;
    if (m < 256)      v = fw_gb[m];
    else if (m < 384) v = fw_cb[m-256];
    else if (m < 640) v = bw_gb[m-384];
    else              v = bw_cb[m-640];
    bias[m] = v;
  }
}

// Bt hi/lo for the proj GEMM + att_w^T hi/lo for the MFMA attention
__global__ void pack_bt(const float* __restrict__ Wxp, short* __restrict__ Bthi,
                        short* __restrict__ Btlo, const float* __restrict__ att_w,
                        short* __restrict__ awt_hi, short* __restrict__ awt_lo) {
  int i = blockIdx.x * 256 + threadIdx.x;
  if (i < NCOL * KP) {
    int k = i % KP, n = i / KP;
    float v = (k < 304) ? Wxp[(size_t)k * NCOL + n] : 0.f;
    unsigned short h = f2bf_rne(v);
    float hf = __uint_as_float((unsigned)h << 16);
    unsigned short lo = f2bf_rne(v - hf);
    Bthi[i] = (short)h;
    Btlo[i] = (short)lo;
    return;
  }
  int j = i - NCOL * KP;
  if (j < 128 * 128) {
    int d = j >> 7, c = j & 127;
    float v = att_w[(size_t)c * 128 + d];   // transpose: awt[d][k=c]
    unsigned short h = f2bf_rne(v);
    float hf = __uint_as_float((unsigned)h << 16);
    unsigned short lo = f2bf_rne(v - hf);
    awt_hi[j] = (short)h;
    awt_lo[j] = (short)lo;
  }
}

__global__ void pack_emb(const float* __restrict__ emb, short* __restrict__ Ahi,
                         short* __restrict__ Alo) {
  size_t i = (size_t)blockIdx.x * 256 + threadIdx.x;
  if (i >= (size_t)V_ * KP) return;
  int k = (int)(i % KP);
  size_t row = i / KP;
  float v = (k < E_) ? emb[row * E_ + k] : 0.f;
  unsigned short h = f2bf_rne(v);
  float hf = __uint_as_float((unsigned)h << 16);
  unsigned short lo = f2bf_rne(v - hf);
  Ahi[i] = (short)h;
  Alo[i] = (short)lo;
}

// ---------------------------------------------------------------------------
// proj = emb @ Wxp via bf16x3 split MFMA (m97 structure).
// Grid is LINEAR (2346 WGs); bijective XCD swizzle (m204 formula) puts all
// 6 n-blocks of one m-tile on the SAME XCD so the 164KB A-tile is read once
// from HBM and 5x from L2 (was 6x HBM with the old (6,391) grid because the
// dispatcher round-robins consecutive blocks across XCDs).
// ---------------------------------------------------------------------------
__global__ __launch_bounds__(256) void gemm_mfma(
    const short* __restrict__ Ahi, const short* __restrict__ Alo,
    const short* __restrict__ Bthi, const short* __restrict__ Btlo,
    float* __restrict__ proj) {
  __shared__ short lds[16384];
  int tid = threadIdx.x, wid = tid >> 6, lane = tid & 63;

  // bijective XCD swizzle: nwg=2346, q=293, r=2
  int bid = blockIdx.x;
  int xcd = bid & 7, idx = bid >> 3;
  int wgid = (xcd < 2 ? xcd * 294 : 588 + (xcd - 2) * 293) + idx;
  int m0 = (wgid / 6) * 128;
  int n0 = (wgid % 6) * 128;

  f32x4 acc[4][4] = {};

  int lr = lane >> 2, lc = lane & 3;
  int q0 = wid * 2, q1 = q0 + 1;
  int r0 = q0 * 16 + lr, r1 = q1 * 16 + lr;
  int am0 = m0 + r0; if (am0 > V_ - 1) am0 = V_ - 1;
  int am1 = m0 + r1; if (am1 > V_ - 1) am1 = V_ - 1;
  size_t gaOff0 = (size_t)am0 * KP + lc * 8;
  size_t gaOff1 = (size_t)am1 * KP + lc * 8;
  size_t gbOff0 = (size_t)(n0 + r0) * KP + lc * 8;
  size_t gbOff1 = (size_t)(n0 + r1) * KP + lc * 8;

  int quad = lane >> 4;
  int arow = (wid >> 1) * 64 + (lane & 15);
  int brow = (wid & 1) * 64 + (lane & 15);

  for (int k0 = 0; k0 < KP; k0 += 32) {
    gload_lds16(Ahi  + gaOff0 + k0, lds +         q0 * 512);
    gload_lds16(Ahi  + gaOff1 + k0, lds +         q1 * 512);
    gload_lds16(Alo  + gaOff0 + k0, lds +  4096 + q0 * 512);
    gload_lds16(Alo  + gaOff1 + k0, lds +  4096 + q1 * 512);
    gload_lds16(Bthi + gbOff0 + k0, lds +  8192 + q0 * 512);
    gload_lds16(Bthi + gbOff1 + k0, lds +  8192 + q1 * 512);
    gload_lds16(Btlo + gbOff0 + k0, lds + 12288 + q0 * 512);
    gload_lds16(Btlo + gbOff1 + k0, lds + 12288 + q1 * 512);
    __syncthreads();

    bf16x8 ah[4], al[4], bh[4], bl[4];
#pragma unroll
    for (int i = 0; i < 4; ++i) {
      ah[i] = *(bf16x8*)&lds[        (arow + i*16) * 32 + quad * 8];
      al[i] = *(bf16x8*)&lds[ 4096 + (arow + i*16) * 32 + quad * 8];
      bh[i] = *(bf16x8*)&lds[ 8192 + (brow + i*16) * 32 + quad * 8];
      bl[i] = *(bf16x8*)&lds[12288 + (brow + i*16) * 32 + quad * 8];
    }
#pragma unroll
    for (int i = 0; i < 4; ++i)
#pragma unroll
      for (int j = 0; j < 4; ++j) {
        acc[i][j] = __builtin_amdgcn_mfma_f32_16x16x32_bf16(ah[i], bh[j], acc[i][j], 0, 0, 0);
        acc[i][j] = __builtin_amdgcn_mfma_f32_16x16x32_bf16(ah[i], bl[j], acc[i][j], 0, 0, 0);
        acc[i][j] = __builtin_amdgcn_mfma_f32_16x16x32_bf16(al[i], bh[j], acc[i][j], 0, 0, 0);
      }
    __syncthreads();
  }

  int colb = n0 + (wid & 1) * 64 + (lane & 15);
  int rowb = m0 + (wid >> 1) * 64 + quad * 4;
#pragma unroll
  for (int i = 0; i < 4; ++i) {
    int rb = rowb + i * 16;
#pragma unroll
    for (int j = 0; j < 4; ++j) {
      int cc = colb + j * 16;
#pragma unroll
      for (int r = 0; r < 4; ++r) {
        int rr = rb + r;
        if (rr < V_) proj[(size_t)rr * NCOL + cc] = acc[i][j][r];
      }
    }
  }
}

// ---------------------------------------------------------------------------
// Fused recurrence + attention. Recurrence phase is the round-0 best-measured
// body (466 us): k-sliced partials, 4 barriers, weights resident, 2 WG/CU.
// After the chain finishes (+ tail zeroing + __syncthreads, which drains
// vmcnt so this WG's own state stores are visible), the SAME WG runs the
// attention for its chain — identical bid->(b,dir,arr) mapping, so the attn
// dispatch disappears and short chains' attention hides under long chains'
// recurrence. LDS is a union of the two phases' layouts (18752 B).
// ---------------------------------------------------------------------------
__global__ __attribute__((amdgpu_flat_work_group_size(256, 256),
                          amdgpu_waves_per_eu(2, 2)))
void recur_attn_kernel(
    const int* __restrict__ ctx, const int* __restrict__ endseq,
    const int* __restrict__ ctx_len, const int* __restrict__ end_len,
    const float* __restrict__ proj, const float* __restrict__ Uall,
    const float* __restrict__ bias, float* __restrict__ states,
    const short* __restrict__ awt_hi, const short* __restrict__ awt_lo,
    const float* __restrict__ att_v, const float* __restrict__ att_b,
    float* __restrict__ feats) {
  __shared__ __align__(16) char smraw[18752];
  // recurrence-phase views (14080 B)
  float* h_s  = (float*)smraw;
  float* rh_s = h_s + 128;
  float* u_s  = rh_s + 128;
  float (*pg)[260] = (float(*)[260])(u_s + 128);
  float (*pc)[132] = (float(*)[132])(pg + 8);
  // attention-phase views (18752 B, overlaid)
  float (*st_s)[132] = (float(*)[132])smraw;
  short (*ah_s)[132] = (short(*)[132])(smraw + 8448);
  short (*al_s)[132] = (short(*)[132])(smraw + 12672);
  float (*spart)[16] = (float(*)[16])(smraw + 16896);
  float* score_s = (float*)(smraw + 17152);
  float* cm = (float*)(smraw + 17216);
  float* cl = cm + 128;
  float* ca = cl + 128;

  int bid = blockIdx.x;
  int tid = threadIdx.x;
  const int* seq; int S, L, b, dir, featOff; float* stbase;
  if (bid < 256) {
    b = bid >> 1; dir = bid & 1;
    seq = ctx + b * SC_; S = SC_; L = ctx_len[b];
    stbase = states + (dir ? SZ_ST_CTX : 0) + (size_t)b * SC_ * C_;
    featOff = dir * 128;
  } else {
    int q = bid - 256; b = q >> 1; dir = q & 1;
    seq = endseq + b * SE_; S = SE_; L = end_len[b];
    stbase = states + 2*SZ_ST_CTX + (dir ? SZ_ST_END : 0) + (size_t)b * SE_ * C_;
    featOff = 256 + dir * 128;
  }
  int dirOff = dir ? 384 : 0;
  int kg = tid >> 5, jg = tid & 31;

  {
    float wg[16][8];
    float wc[16][4];
#pragma unroll
    for (int kk = 0; kk < 16; ++kk) {
      const float* up = Uall + (size_t)(kg*16 + kk) * NCOL + dirOff;
      float4 w0 = *(const float4*)(up + jg*8);
      float4 w1 = *(const float4*)(up + jg*8 + 4);
      wg[kk][0]=w0.x; wg[kk][1]=w0.y; wg[kk][2]=w0.z; wg[kk][3]=w0.w;
      wg[kk][4]=w1.x; wg[kk][5]=w1.y; wg[kk][6]=w1.z; wg[kk][7]=w1.w;
      float4 wv = *(const float4*)(up + 256 + jg*4);
      wc[kk][0]=wv.x; wc[kk][1]=wv.y; wc[kk][2]=wv.z; wc[kk][3]=wv.w;
    }
    float bias_g = bias[dirOff + tid];
    float bias_c = (tid < 128) ? bias[dirOff + 256 + tid] : 0.f;

    if (tid < 128) h_s[tid] = 0.f;
    __syncthreads();

    int pos0 = dir ? (L - 1) : 0;
    int tok0 = seq[pos0];
    const float* xr0 = proj + (size_t)tok0 * NCOL + dirOff;
    float xg = xr0[tid];
    float xc = (tid < 128) ? xr0[256 + tid] : 0.f;

    for (int t = 0; t < L; ++t) {
      float xg_n = 0.f, xc_n = 0.f;
      if (t + 1 < L) {
        int pos_n = dir ? (L - 2 - t) : (t + 1);
        int tok_n = seq[pos_n];
        const float* xr = proj + (size_t)tok_n * NCOL + dirOff;
        xg_n = xr[tid];
        xc_n = (tid < 128) ? xr[256 + tid] : 0.f;
      }

      float a[8] = {0.f,0.f,0.f,0.f,0.f,0.f,0.f,0.f};
      const float4* h4 = (const float4*)h_s;
#pragma unroll
      for (int q = 0; q < 4; ++q) {
        float4 hv = h4[kg*4 + q];
        float he[4] = {hv.x, hv.y, hv.z, hv.w};
#pragma unroll
        for (int e = 0; e < 4; ++e)
#pragma unroll
          for (int jj = 0; jj < 8; ++jj)
            a[jj] += he[e] * wg[q*4 + e][jj];
      }
      *(float4*)(&pg[kg][jg*8])     = make_float4(a[0], a[1], a[2], a[3]);
      *(float4*)(&pg[kg][jg*8 + 4]) = make_float4(a[4], a[5], a[6], a[7]);
      __syncthreads();   // B1

      float g = xg + bias_g;
#pragma unroll
      for (int k2 = 0; k2 < 8; ++k2) g += pg[k2][tid];
      g = fast_sigmoid(g);

      float h_old = 0.f;
      if (tid < 128) { h_old = h_s[tid]; rh_s[tid] = g * h_old; }
      else           { u_s[tid - 128] = g; }
      __syncthreads();   // B2

      float ac[4] = {0.f, 0.f, 0.f, 0.f};
      const float4* rh4 = (const float4*)rh_s;
#pragma unroll
      for (int q = 0; q < 4; ++q) {
        float4 rv = rh4[kg*4 + q];
        float re[4] = {rv.x, rv.y, rv.z, rv.w};
#pragma unroll
        for (int e = 0; e < 4; ++e)
#pragma unroll
          for (int jj = 0; jj < 4; ++jj)
            ac[jj] += re[e] * wc[q*4 + e][jj];
      }
      *(float4*)(&pc[kg][jg*4]) = make_float4(ac[0], ac[1], ac[2], ac[3]);
      __syncthreads();   // B3

      if (tid < 128) {
        float cs = xc + bias_c;
#pragma unroll
        for (int k2 = 0; k2 < 8; ++k2) cs += pc[k2][tid];
        float c = fast_tanh(cs);
        float u = u_s[tid];
        float hn = u * h_old + (1.f - u) * c;
        h_s[tid] = hn;
        int pos = dir ? (L - 1 - t) : t;
        stbase[(size_t)pos * C_ + tid] = hn;
      }
      __syncthreads();   // B4
      xg = xg_n; xc = xc_n;
    }

    for (int i = L * C_ + tid; i < S * C_; i += 256) stbase[i] = 0.f;
  }
  __syncthreads();   // drain stores (vmcnt 0 before barrier) + retire recur LDS

  // ---------------- attention phase (same chain) ----------------
  const float* stb = stbase;
  int w = tid >> 6, lane = tid & 63;
  int quad = lane >> 4, l15 = lane & 15;

  int d0 = 32 * w + l15, d1 = d0 + 16;
  bf16x8 bh0[4], bh1[4], bl0[4], bl1[4];
#pragma unroll
  for (int kt = 0; kt < 4; ++kt) {
    bh0[kt] = *(const bf16x8*)&awt_hi[d0*128 + kt*32 + quad*8];
    bh1[kt] = *(const bf16x8*)&awt_hi[d1*128 + kt*32 + quad*8];
    bl0[kt] = *(const bf16x8*)&awt_lo[d0*128 + kt*32 + quad*8];
    bl1[kt] = *(const bf16x8*)&awt_lo[d1*128 + kt*32 + quad*8];
  }
  float vv0 = att_v[d0], vv1 = att_v[d1];
  float bb0 = att_b[d0], bb1 = att_b[d1];

  int c = tid & 127, half = tid >> 7;
  float m = -1e30f, lsum = 0.f, acc = 0.f;

  int lrow = tid >> 4, lcol = (tid & 15) * 8;
  float4 p0, p1;
  {
    const float* src = stb + (size_t)lrow * C_ + lcol;
    p0 = *(const float4*)(src);
    p1 = *(const float4*)(src + 4);
  }

  int nchunks = S >> 4;
  for (int ch = 0; ch < nchunks; ++ch) {
    __syncthreads();   // A0: prior chunk's LDS readers done
    float f[8] = {p0.x, p0.y, p0.z, p0.w, p1.x, p1.y, p1.z, p1.w};
    short hi8[8], lo8[8];
#pragma unroll
    for (int j = 0; j < 8; ++j) {
      unsigned short h = f2bf_rne(f[j]);
      float hf = __uint_as_float((unsigned)h << 16);
      hi8[j] = (short)h;
      lo8[j] = (short)f2bf_rne(f[j] - hf);
    }
    *(float4*)(&st_s[lrow][lcol])     = p0;
    *(float4*)(&st_s[lrow][lcol + 4]) = p1;
    *(bf16x8*)(&ah_s[lrow][lcol]) = *(bf16x8*)hi8;
    *(bf16x8*)(&al_s[lrow][lcol]) = *(bf16x8*)lo8;
    if (ch + 1 < nchunks) {
      const float* src = stb + (size_t)((ch + 1) * 16 + lrow) * C_ + lcol;
      p0 = *(const float4*)(src);
      p1 = *(const float4*)(src + 4);
    }
    __syncthreads();   // A1: staging visible

    f32x4 ac0 = {0.f, 0.f, 0.f, 0.f}, ac1 = {0.f, 0.f, 0.f, 0.f};
#pragma unroll
    for (int kt = 0; kt < 4; ++kt) {
      bf16x8 a_hi = *(bf16x8*)&ah_s[l15][kt*32 + quad*8];
      bf16x8 a_lo = *(bf16x8*)&al_s[l15][kt*32 + quad*8];
      ac0 = __builtin_amdgcn_mfma_f32_16x16x32_bf16(a_hi, bh0[kt], ac0, 0, 0, 0);
      ac0 = __builtin_amdgcn_mfma_f32_16x16x32_bf16(a_hi, bl0[kt], ac0, 0, 0, 0);
      ac0 = __builtin_amdgcn_mfma_f32_16x16x32_bf16(a_lo, bh0[kt], ac0, 0, 0, 0);
      ac1 = __builtin_amdgcn_mfma_f32_16x16x32_bf16(a_hi, bh1[kt], ac1, 0, 0, 0);
      ac1 = __builtin_amdgcn_mfma_f32_16x16x32_bf16(a_hi, bl1[kt], ac1, 0, 0, 0);
      ac1 = __builtin_amdgcn_mfma_f32_16x16x32_bf16(a_lo, bh1[kt], ac1, 0, 0, 0);
    }

    float part[4];
#pragma unroll
    for (int r = 0; r < 4; ++r)
      part[r] = fast_tanh(ac0[r] + bb0) * vv0 + fast_tanh(ac1[r] + bb1) * vv1;
#pragma unroll
    for (int mask = 1; mask <= 8; mask <<= 1)
#pragma unroll
      for (int r = 0; r < 4; ++r)
        part[r] += __shfl_xor(part[r], mask, 64);
    if (l15 == 0) {
#pragma unroll
      for (int r = 0; r < 4; ++r) spart[w][quad*4 + r] = part[r];
    }
    __syncthreads();   // A2: spart visible
    if (tid < 16)
      score_s[tid] = spart[0][tid] + spart[1][tid] + spart[2][tid] + spart[3][tid];
    __syncthreads();   // A3: scores visible

    float srow[8]; float smax = m;
#pragma unroll
    for (int r = 0; r < 8; ++r) { srow[r] = score_s[half*8 + r]; smax = fmaxf(smax, srow[r]); }
    float scale = __expf(m - smax);
    acc *= scale; lsum *= scale; m = smax;
#pragma unroll
    for (int r = 0; r < 8; ++r) {
      float wgt = __expf(srow[r] - m);
      lsum += wgt;
      acc += wgt * st_s[half*8 + r][c];
    }
  }

  __syncthreads();
  if (half == 1) { cm[c] = m; cl[c] = lsum; ca[c] = acc; }
  __syncthreads();
  if (half == 0) {
    float m1 = cm[c], l1 = cl[c], a1 = ca[c];
    float M = fmaxf(m, m1);
    float w0 = __expf(m - M), w1 = __expf(m1 - M);
    feats[b * 512 + featOff + c] = (acc * w0 + a1 * w1) / (lsum * w0 + l1 * w1);
  }
}

// ---------------------------------------------------------------------------
// Head
// ---------------------------------------------------------------------------
__global__ __launch_bounds__(128) void head_kernel(
    const float* __restrict__ feats, const float* __restrict__ hid_w,
    const float* __restrict__ hid_b, const float* __restrict__ out_w,
    const float* __restrict__ out_b, float* __restrict__ out) {
  __shared__ __align__(16) float f_s[512];
  __shared__ float part[2];
  int b = blockIdx.x, tid = threadIdx.x;
  for (int i = tid; i < 512; i += 128) f_s[i] = feats[b * 512 + i];
  __syncthreads();
  float h = hid_b[tid];
  for (int k = 0; k < 512; ++k) h += f_s[k] * hid_w[k * 128 + tid];
  h = fmaxf(h, 0.f);
  float p = h * out_w[tid];
#pragma unroll
  for (int off = 32; off > 0; off >>= 1) p += __shfl_xor(p, off, 64);
  if ((tid & 63) == 0) part[tid >> 6] = p;
  __syncthreads();
  if (tid == 0) out[b] = part[0] + part[1] + out_b[0];
}

// ---------------------------------------------------------------------------
extern "C" void kernel_launch(void* const* d_in, const int* in_sizes, int n_in,
                              void* d_out, int out_size, void* d_ws, size_t ws_size,
                              hipStream_t stream) {
  const int*   ctx     = (const int*)d_in[0];
  const int*   endseq  = (const int*)d_in[1];
  const int*   ctx_len = (const int*)d_in[2];
  const int*   end_len = (const int*)d_in[3];
  const float* emb     = (const float*)d_in[4];
  const float* fw_gw   = (const float*)d_in[5];
  const float* fw_gb   = (const float*)d_in[6];
  const float* fw_cw   = (const float*)d_in[7];
  const float* fw_cb   = (const float*)d_in[8];
  const float* bw_gw   = (const float*)d_in[9];
  const float* bw_gb   = (const float*)d_in[10];
  const float* bw_cw   = (const float*)d_in[11];
  const float* bw_cb   = (const float*)d_in[12];
  const float* att_v   = (const float*)d_in[13];
  const float* att_w   = (const float*)d_in[14];
  const float* att_b   = (const float*)d_in[15];
  const float* hid_w   = (const float*)d_in[16];
  const float* hid_b   = (const float*)d_in[17];
  const float* out_w   = (const float*)d_in[18];
  const float* out_b   = (const float*)d_in[19];
  float* ws  = (float*)d_ws;
  float* out = (float*)d_out;

  short* Ahi    = (short*)(ws + OFF_ST);
  short* Alo    = Ahi + (size_t)V_ * KP;
  short* Bthi   = (short*)(ws + OFF_BT);
  short* Btlo   = Bthi + (size_t)NCOL * KP;
  short* awt_hi = (short*)(ws + OFF_AWT);
  short* awt_lo = awt_hi + 128 * 128;

  pack_kernel<<<1299, 256, 0, stream>>>(fw_gw, fw_gb, fw_cw, fw_cb,
                                        bw_gw, bw_gb, bw_cw, bw_cb, ws);
  pack_bt<<<(NCOL * KP + 128 * 128 + 255) / 256, 256, 0, stream>>>(
      ws + OFF_WXP, Bthi, Btlo, att_w, awt_hi, awt_lo);
  pack_emb<<<(int)(((size_t)V_ * KP + 255) / 256), 256, 0, stream>>>(emb, Ahi, Alo);

  gemm_mfma<<<2346, 256, 0, stream>>>(Ahi, Alo, Bthi, Btlo, ws + OFF_PROJ);

  recur_attn_kernel<<<512, 256, 0, stream>>>(ctx, endseq, ctx_len, end_len,
                                             ws + OFF_PROJ, ws + OFF_UALL,
                                             ws + OFF_BIAS, ws + OFF_ST,
                                             awt_hi, awt_lo, att_v, att_b,
                                             ws + OFF_FEATS);

  head_kernel<<<128, 128, 0, stream>>>(ws + OFF_FEATS, hid_w, hid_b,
                                       out_w, out_b, out);
}